// Round 11
// baseline (339.534 us; speedup 1.0000x reference)
//
#include <hip/hip_runtime.h>
#include <math.h>
#include <stdint.h>

#define NN   50000
#define NPAD 50048          // 391 * 128
#define CD   256
#define DEG  16

typedef _Float16 f16;
typedef _Float16 f16x2 __attribute__((ext_vector_type(2)));
typedef _Float16 f16x4 __attribute__((ext_vector_type(4)));
typedef _Float16 f16x8 __attribute__((ext_vector_type(8)));
typedef float    f32x4 __attribute__((ext_vector_type(4)));

typedef const uint32_t __attribute__((address_space(1)))* gptr_t;
typedef uint32_t       __attribute__((address_space(3)))* lptr_t;

// Head-major layout for Q,K,V: elem(h, n, d) = (h*NPAD + n)*32 + d

#define CONVH_BLOCKS 6256   // NPAD*CD/8/256

// ---------------------------------------------------------------------------
// Fused conversion kernel: blocks [0, CONVH_BLOCKS) convert h -> f16 (padded);
// blocks [CONVH_BLOCKS, +768) transpose W -> Wt f16 [n][k].
// ---------------------------------------------------------------------------
__global__ __launch_bounds__(256) void conv_hw(
    const float* __restrict__ h,
    const float* __restrict__ Wq, const float* __restrict__ Wk,
    const float* __restrict__ Wv,
    f16* __restrict__ o, f16* __restrict__ Wt)
{
    int b = blockIdx.x;
    if (b < CONVH_BLOCKS) {
        size_t i8 = ((size_t)b * 256 + threadIdx.x) * 8;
        if (i8 >= (size_t)NPAD * CD) return;
        f16x8 r;
        if (i8 < (size_t)NN * CD) {
            float4 a = ((const float4*)(h + i8))[0];
            float4 c = ((const float4*)(h + i8))[1];
            r[0] = (f16)a.x; r[1] = (f16)a.y; r[2] = (f16)a.z; r[3] = (f16)a.w;
            r[4] = (f16)c.x; r[5] = (f16)c.y; r[6] = (f16)c.z; r[7] = (f16)c.w;
        } else {
            r = (f16x8)(f16)0.f;
        }
        *(f16x8*)(o + i8) = r;
    } else {
        int bb = b - CONVH_BLOCKS;          // 0..767
        int m  = bb >> 8;                   // matrix 0..2
        int n  = bb & 255;
        const float* W = (m == 0) ? Wq : (m == 1) ? Wk : Wv;
        int k = threadIdx.x;
        Wt[(size_t)m * 65536 + n * 256 + k] = (f16)W[k * 256 + n];
    }
}

// ---------------------------------------------------------------------------
// Q|K|V = h16 @ W  via mfma_f32_16x16x32_f16.  Round-6 GEMM structure
// (proven fastest): tile 128x128, BK=64, grid (391, 2, 3), LDS 32KB,
// XOR slot swizzle.  RoPE fused into the epilogue for z<2 (Q,K)
// (verified passing in round 10).  V (z=2) stored unrotated.
// ---------------------------------------------------------------------------
__global__ __launch_bounds__(256) void gemm16(
    const f16* __restrict__ h16, const f16* __restrict__ Wt,
    const float* __restrict__ pos,
    f16* __restrict__ Qo, f16* __restrict__ Ko, f16* __restrict__ Vo)
{
    __shared__ __align__(16) char lds[32768];   // A: [0,16K) B: [16K,32K)

    const int t    = threadIdx.x;
    const int lane = t & 63;
    const int wid  = t >> 6;
    const int tm   = blockIdx.x;
    const int nc0  = blockIdx.y * 128;
    const int z    = blockIdx.z;

    const f16* B = Wt + (size_t)z * 65536;
    f16* O = (z == 0) ? Qo : (z == 1) ? Ko : Vo;

    const int r15 = lane & 15;
    const int g4  = lane >> 4;
    const int l7  = lane & 7;
    const int wm  = (wid >> 1) * 64;
    const int wn  = (wid & 1) * 64;

    f32x4 acc[4][4];
#pragma unroll
    for (int i = 0; i < 4; ++i)
#pragma unroll
        for (int j = 0; j < 4; ++j) acc[i][j] = (f32x4)0.f;

    for (int kb = 0; kb < 4; ++kb) {
        // ---- stage A,B tiles (swizzled source, linear LDS dest) ----
#pragma unroll
        for (int i = 0; i < 4; ++i) {
            int L    = i * 256 + t;
            int row  = L >> 3;                    // 0..127
            int slot = (L & 7) ^ (row & 7);       // source slot
            const char* srcA = (const char*)h16 +
                ((size_t)(tm * 128 + row)) * 512 + kb * 128 + slot * 16;
            const char* srcB = (const char*)B +
                ((size_t)(nc0 + row)) * 512 + kb * 128 + slot * 16;
            uint32_t ldsOff = (uint32_t)(i * 256 + (t & 192)) * 16;
            __builtin_amdgcn_global_load_lds((gptr_t)srcA, (lptr_t)(lds + ldsOff), 16, 0, 0);
            __builtin_amdgcn_global_load_lds((gptr_t)srcB, (lptr_t)(lds + 16384 + ldsOff), 16, 0, 0);
        }
        __syncthreads();                          // drains vmcnt before barrier

        // ---- compute ----
#pragma unroll
        for (int ks = 0; ks < 2; ++ks) {
            const int sl = (ks * 4 + g4) ^ l7;    // swizzled read slot
            f16x8 a[4], b[4];
#pragma unroll
            for (int am = 0; am < 4; ++am) {
                int row = wm + am * 16 + r15;
                a[am] = *(const f16x8*)(lds + row * 128 + sl * 16);
            }
#pragma unroll
            for (int bn = 0; bn < 4; ++bn) {
                int row = wn + bn * 16 + r15;
                b[bn] = *(const f16x8*)(lds + 16384 + row * 128 + sl * 16);
            }
#pragma unroll
            for (int am = 0; am < 4; ++am)
#pragma unroll
                for (int bn = 0; bn < 4; ++bn)
                    acc[am][bn] = __builtin_amdgcn_mfma_f32_16x16x32_f16(
                        a[am], b[bn], acc[am][bn], 0, 0, 0);
        }
        if (kb < 3) __syncthreads();              // protect LDS before restage
    }

    // ---- epilogue: C row = (lane>>4)*4 + reg, col = lane&15; head-major out
    const float INVF[8] = {1.f, 0.31622776601683794f, 0.1f, 0.031622776601683794f,
                           0.01f, 0.0031622776601683794f, 0.001f, 0.00031622776601683794f};
    const float invf = INVF[l7] * 64.f;
    const bool  hi   = (r15 & 8) != 0;

#pragma unroll
    for (int am = 0; am < 4; ++am) {
        if (z < 2) {
            // fused RoPE for this am's 4 rows
            float sx[4], cx[4], sy[4], cy[4];
#pragma unroll
            for (int j = 0; j < 4; ++j) {
                int gm = tm * 128 + wm + am * 16 + g4 * 4 + j;
                int gc = (gm < NN) ? gm : 0;
                float2 p = *(const float2*)(pos + 2 * gc);
                __sincosf(p.x * invf, &sx[j], &cx[j]);
                __sincosf(p.y * invf, &sy[j], &cy[j]);
            }
#pragma unroll
            for (int bn = 0; bn < 4; ++bn) {
                int col = nc0 + wn + bn * 16 + r15;   // 0..255
                int hh  = col >> 5, dd = col & 31;
                const bool yhalf = (dd & 16) != 0;
#pragma unroll
                for (int j = 0; j < 4; ++j) {
                    float v    = acc[am][bn][j];
                    float part = __shfl_xor(v, 8);
                    float c = yhalf ? cy[j] : cx[j];
                    float s = yhalf ? sy[j] : sx[j];
                    float res = hi ? (v * c + part * s) : (v * c - part * s);
                    int gm = tm * 128 + wm + am * 16 + g4 * 4 + j;
                    if (gm < NN)
                        O[((size_t)hh * NPAD + gm) * 32 + dd] = (f16)res;
                }
            }
        } else {
#pragma unroll
            for (int bn = 0; bn < 4; ++bn) {
                int col = nc0 + wn + bn * 16 + r15;
                int hh  = col >> 5, dd = col & 31;
#pragma unroll
                for (int j = 0; j < 4; ++j) {
                    int gm = tm * 128 + wm + am * 16 + g4 * 4 + j;
                    if (gm < NN)
                        O[((size_t)hh * NPAD + gm) * 32 + dd] = (f16)acc[am][bn][j];
                }
            }
        }
    }
}

// ---------------------------------------------------------------------------
// edgeF: FUSED edge attention (scoreK + aggV in one wave, no scores buffer).
// One wave per (node, head); grid 100000 blocks (12500*8), head = b&7
// (XCD-pinned for L2 residency), 4 waves = 4 consecutive nodes.
// Phase 1 (scoreK v2, proven): lane=(edge j=l>>2, piece p=l&3); 4 lanes per
//   64B K row; 4x fdot2; shfl_xor(1,2) -> w_j in lanes 4j..4j+3.
//   z = xor-reduce(w, {4,8,16,32}) (each group contributes once per lane&3
//   slice -> every lane ends with sum_j w_j).
// Phase 2: lane owns dim d=l&31 (2 copies); 16 unrolled edges: broadcast
//   (s_j, w_j) from lane 4j via __shfl, gather ONE f16 of V per lane
//   (each V row = exactly one 64B line per instr), in-register fma.
//   Lanes < 32 store the 128B f32 output row.
// Wave-local only: no LDS, no barriers.
// ---------------------------------------------------------------------------
__global__ __launch_bounds__(256) void edgeF(
    const f16* __restrict__ Q, const f16* __restrict__ K,
    const f16* __restrict__ V,
    const int* __restrict__ src, float* __restrict__ out)
{
    const int b   = blockIdx.x;                     // 0..99999
    const int h   = b & 7;
    const int n   = (b >> 3) * 4 + (threadIdx.x >> 6);   // 12500*4 = 50000
    const int l   = threadIdx.x & 63;
    const int j   = l >> 2;                         // edge 0..15
    const int p   = l & 3;                          // 16B piece 0..3

    const int s = src[n * DEG + j];

    // ---- phase 1: scores ----
    f16x8 q8 = *(const f16x8*)(Q + ((size_t)h * NPAD + n) * 32 + p * 8);
    f16x8 k8 = *(const f16x8*)(K + ((size_t)h * NPAD + s) * 32 + p * 8);

    const f16x2* qp = (const f16x2*)&q8;
    const f16x2* kp = (const f16x2*)&k8;
    float d = 0.f;
#if __has_builtin(__builtin_amdgcn_fdot2)
    d = __builtin_amdgcn_fdot2(qp[0], kp[0], d, false);
    d = __builtin_amdgcn_fdot2(qp[1], kp[1], d, false);
    d = __builtin_amdgcn_fdot2(qp[2], kp[2], d, false);
    d = __builtin_amdgcn_fdot2(qp[3], kp[3], d, false);
#else
#pragma unroll
    for (int u = 0; u < 4; ++u)
        d += (float)qp[u].x * (float)kp[u].x + (float)qp[u].y * (float)kp[u].y;
#endif
    d += __shfl_xor(d, 1);          // combine pieces within 4-lane group
    d += __shfl_xor(d, 2);

    const float w = __expf(fminf(fmaxf(d * 0.17677669529663687f, -5.f), 5.f));

    // z = sum_j w_j : groups are lane bits 2..5; xor-reduce over them
    float z = w;
    z += __shfl_xor(z, 4);
    z += __shfl_xor(z, 8);
    z += __shfl_xor(z, 16);
    z += __shfl_xor(z, 32);

    // ---- phase 2: weighted V aggregation, lane = dim ----
    const int dim = l & 31;                          // 2 copies of each dim
    const f16* Vh = V + (size_t)h * NPAD * 32;

    float acc = 0.f;
#pragma unroll
    for (int e = 0; e < DEG; ++e) {
        int   se = __shfl(s, e * 4);                 // broadcast edge src
        float we = __shfl(w, e * 4);                 // broadcast edge weight
        acc += we * (float)Vh[(size_t)se * 32 + dim];
    }

    if (l < 32)
        out[(size_t)n * CD + h * 32 + dim] = acc / z;
}

// ---------------------------------------------------------------------------
extern "C" void kernel_launch(void* const* d_in, const int* in_sizes, int n_in,
                              void* d_out, int out_size, void* d_ws, size_t ws_size,
                              hipStream_t stream)
{
    const float* h   = (const float*)d_in[0];
    const float* pos = (const float*)d_in[1];
    const float* Wq  = (const float*)d_in[2];
    const float* Wk  = (const float*)d_in[3];
    const float* Wv  = (const float*)d_in[4];
    const int*   src = (const int*)d_in[5];
    float* out = (float*)d_out;

    char* w = (char*)d_ws;
    f16*   h16    = (f16*)w;                              // 25,624,576 B
    f16*   Wt     = (f16*)(w + 25624576);                 //    393,216 B
    f16*   Qb     = (f16*)(w + 26017792);                 // 25,624,576 B
    f16*   Kb     = (f16*)(w + 51642368);
    f16*   Vb     = (f16*)(w + 77266944);                 // end ~98.1 MiB

    conv_hw<<<CONVH_BLOCKS + 768, 256, 0, stream>>>(h, Wq, Wk, Wv, h16, Wt);
    gemm16<<<dim3(391, 2, 3), 256, 0, stream>>>(h16, Wt, pos, Qb, Kb, Vb);
    edgeF<<<100000, 256, 0, stream>>>(Qb, Kb, Vb, src, out);
}